// Round 6
// baseline (601.069 us; speedup 1.0000x reference)
//
#include <hip/hip_runtime.h>
#include <hip/hip_bf16.h>

#define Bb 1024
#define NN 50
#define KK 8
#define DD 128
#define CC 51
#define LDK 136   // bf16 elems per LDS row (272 B, 16B-aligned)

typedef __attribute__((ext_vector_type(8))) short short8;
typedef __attribute__((ext_vector_type(4))) float f32x4;

__device__ __forceinline__ unsigned short f2bf(float f) {
  union { float f; unsigned int u; } un; un.f = f;
  unsigned int r = un.u + 0x7fffu + ((un.u >> 16) & 1u);
  return (unsigned short)(r >> 16);
}
__device__ __forceinline__ float bf2f(unsigned short h) {
  union { unsigned int u; float f; } un; un.u = ((unsigned int)h) << 16;
  return un.f;
}

// ---------------- workspace layout (bytes) ----------------
static constexpr size_t SZ_BCD   = (size_t)Bb * CC * DD;            // 6684672
static constexpr size_t OFF_SUBG = 0;                               // f32 B*50*128 (26.2MB)
static constexpr size_t OFF_XBF  = 0;                               // bf16 overlay (subg dead after k2)
static constexpr size_t OFF_Y    = (size_t)Bb * NN * DD * 4;        // Ybf bf16
static constexpr size_t OFF_H1   = OFF_Y + SZ_BCD * 2;              // H1bf bf16
static constexpr size_t OFF_BN   = OFF_H1 + SZ_BCD * 2;             // 1KB accums
static constexpr size_t OFF_H2   = OFF_BN + 1024;                   // f32 B*128
static constexpr size_t OFF_M    = OFF_H2 + (size_t)Bb * DD * 4;    // f32 128*128+129

// ---------------- K0: M = attW^T attW, u = attW^T b, bbsq ----------------
__global__ __launch_bounds__(128) void k0_prep(
    const float* __restrict__ attW, const float* __restrict__ attb,
    float* __restrict__ M) {
  int d = blockIdx.x, e = threadIdx.x;
  float m = 0.f, ub = 0.f;
#pragma unroll 4
  for (int k = 0; k < DD; ++k) {
    float wd = attW[(size_t)k * DD + d];   // uniform per block
    m  += attW[(size_t)k * DD + e] * wd;   // coalesced
    ub += wd * attb[k];
  }
  M[(size_t)e * DD + d] = m;
  if (e == 0) M[DD * DD + d] = ub;
  if (d == 0 && e == 0) {
    float bb = 0.f;
    for (int k = 0; k < DD; ++k) bb += attb[k] * attb[k];
    M[DD * DD + DD] = bb;
  }
}

// ---------------- K1: per-(n,b) neighbor gather -> subg (f32) ----------------
__global__ __launch_bounds__(64) void k1_gather(
    const int* __restrict__ neb, const int* __restrict__ nebr,
    const float* __restrict__ entW, const float* __restrict__ relW,
    float* __restrict__ subg) {
  int n = blockIdx.x, b = blockIdx.y, lane = threadIdx.x;
  int e = neb[b * NN + n];                            // block-uniform -> scalar
  float2 ev = ((const float2*)(entW + (size_t)e * DD))[lane];
  const int* rb = nebr + ((size_t)(b * NN + n)) * KK; // block-uniform base
  float rx = 0.f, ry = 0.f;
#pragma unroll
  for (int k = 0; k < KK; ++k) {
    float2 rv = ((const float2*)(relW + (size_t)rb[k] * DD))[lane];
    rx += rv.x; ry += rv.y;
  }
  float2 s;
  s.x = 0.5f * (ev.x + rx * 0.125f);
  s.y = 0.5f * (ev.y + ry * 0.125f);
  ((float2*)(subg + ((size_t)(b * NN + n)) * DD))[lane] = s;
}

// ---------------- K2: attention (Mext algebra) + Y(bf16) + hrt outs ----------------
__global__ __launch_bounds__(256) void k2_att(
    const int* __restrict__ hrt, const float* __restrict__ entW,
    const float* __restrict__ relW, const float* __restrict__ subg,
    const float* __restrict__ Mext, unsigned short* __restrict__ Ybf,
    float* __restrict__ out) {
  int b = blockIdx.x, t = threadIdx.x;   // 256 threads
  __shared__ float ss[DD], sw[DD], sl[64];
  __shared__ float cval;
  __shared__ float sub[NN * 132];
  // hrt gathers + sum_hrt (threads 0..31)
  if (t < 32) {
    int hi = hrt[b * 3 + 0], ri = hrt[b * 3 + 1], ti = hrt[b * 3 + 2];
    float4 hv = ((const float4*)(entW + (size_t)hi * DD))[t];
    float4 tv = ((const float4*)(entW + (size_t)ti * DD))[t];
    float4 rv = ((const float4*)(relW + (size_t)ri * DD))[t];
    ((float4*)(out + (size_t)b * DD))[t] = hv;
    ((float4*)(out + (size_t)Bb * DD + (size_t)b * DD))[t] = tv;
    ((float4*)(out + (size_t)2 * Bb * DD + (size_t)b * DD))[t] = rv;
    const float inv3 = 1.f / 3.f;
    float4 s;
    s.x = (hv.x + tv.x + rv.x) * inv3;
    s.y = (hv.y + tv.y + rv.y) * inv3;
    s.z = (hv.z + tv.z + rv.z) * inv3;
    s.w = (hv.w + tv.w + rv.w) * inv3;
    ((float4*)ss)[t] = s;
  }
  // stage subg (coalesced float4)
  for (int idx = t; idx < NN * 32; idx += 256) {
    int r = idx >> 5, c4 = idx & 31;
    float4 v = ((const float4*)(subg + ((size_t)(b * NN + r)) * DD))[c4];
    ((float4*)(sub + r * 132))[c4] = v;
  }
  __syncthreads();
  // w = M.s + u  (coalesced columns of symmetric M); c = s.u + bbsq
  if (t < DD) {
    float w = 0.f;
#pragma unroll 4
    for (int e = 0; e < DD; ++e) w += Mext[(size_t)e * DD + t] * ss[e];
    sw[t] = w + Mext[DD * DD + t];
  }
  if (t >= 128 && t < 192) {
    int l = t - 128;
    const float* u = Mext + DD * DD;
    float v = ss[l] * u[l] + ss[l + 64] * u[l + 64];
#pragma unroll
    for (int m = 1; m < 64; m <<= 1) v += __shfl_xor(v, m);
    if (l == 0) cval = v + u[DD];
  }
  __syncthreads();
  // logits: 4 threads per row
  if (t < NN * 4) {
    int n = t >> 2, q = t & 3;
    const float* sg = sub + n * 132 + q * 32;
    const float* wq = sw + q * 32;
    float L = 0.f;
#pragma unroll 8
    for (int e = 0; e < 32; ++e) L += sg[e] * wq[e];
    L += __shfl_xor(L, 1);
    L += __shfl_xor(L, 2);
    if (q == 0) {
      L += cval;
      sl[n] = (L > 0.f) ? L : 0.01f * L;
    }
  }
  __syncthreads();
  // softmax over 50 (wave 0)
  if (t < 64) {
    float v = (t < NN) ? sl[t] : -1e30f;
    float mx = v;
#pragma unroll
    for (int m = 1; m < 64; m <<= 1) mx = fmaxf(mx, __shfl_xor(mx, m));
    float e = (t < NN) ? __expf(v - mx) : 0.f;
    float sm = e;
#pragma unroll
    for (int m = 1; m < 64; m <<= 1) sm += __shfl_xor(sm, m);
    if (t < NN) sl[t] = e / sm;
  }
  __syncthreads();
  // Y row 0 = sum_hrt
  if (t < 128) Ybf[(size_t)b * CC * DD + t] = f2bf(ss[t]);
  // rows 1..50 = att[n]*subg[n]
  for (int idx = t; idx < NN * 64; idx += 256) {
    int n = idx >> 6, c2 = (idx & 63) * 2;
    float a = sl[n];
    const float* sg = sub + n * 132 + c2;
    unsigned int pk = (unsigned int)f2bf(a * sg[0]) |
                      ((unsigned int)f2bf(a * sg[1]) << 16);
    *(unsigned int*)(Ybf + ((size_t)(b * CC + 1 + n)) * DD + c2) = pk;
  }
}

// ---------------- K3: X(bf16) = Y @ gcn_W^T + gcn_b  via bf16 MFMA ----------------
__global__ __launch_bounds__(256) void k3_gemm(
    const unsigned short* __restrict__ Ybf, const float* __restrict__ gcnW,
    const float* __restrict__ gcnb, unsigned short* __restrict__ Xbf) {
  __shared__ unsigned short Al[128 * LDK];
  __shared__ unsigned short Bl[DD * LDK];
  int t = threadIdx.x;
  size_t row0 = (size_t)blockIdx.x * 128;
  for (int idx = t; idx < 2048; idx += 256) {
    int r = idx >> 4, c = idx & 15;
    uint4 v = ((const uint4*)(Ybf + (row0 + r) * DD))[c];
    *((uint4*)(Al + r * LDK + c * 8)) = v;
  }
  for (int idx = t; idx < 4096; idx += 256) {
    int d = idx >> 5, g = idx & 31;
    float4 v = ((const float4*)(gcnW + (size_t)d * DD))[g];
    ushort4 p;
    p.x = f2bf(v.x); p.y = f2bf(v.y); p.z = f2bf(v.z); p.w = f2bf(v.w);
    *((ushort4*)(Bl + d * LDK + g * 4)) = p;
  }
  __syncthreads();
  int wv = t >> 6, lane = t & 63;
  int m16 = lane & 15;
  int q8 = (lane >> 4) * 8;
  f32x4 acc[2][8] = {};
  const unsigned short* Abase = Al + (wv * 32 + m16) * LDK + q8;
  const unsigned short* Bbase = Bl + m16 * LDK + q8;
#pragma unroll
  for (int ks = 0; ks < 4; ++ks) {
    short8 a0 = *(const short8*)(Abase + ks * 32);
    short8 a1 = *(const short8*)(Abase + 16 * LDK + ks * 32);
#pragma unroll
    for (int nt = 0; nt < 8; ++nt) {
      short8 bb = *(const short8*)(Bbase + nt * 16 * LDK + ks * 32);
      acc[0][nt] = __builtin_amdgcn_mfma_f32_16x16x32_bf16(a0, bb, acc[0][nt], 0, 0, 0);
      acc[1][nt] = __builtin_amdgcn_mfma_f32_16x16x32_bf16(a1, bb, acc[1][nt], 0, 0, 0);
    }
  }
  int qd = (lane >> 4) * 4;
#pragma unroll
  for (int rt = 0; rt < 2; ++rt) {
#pragma unroll
    for (int nt = 0; nt < 8; ++nt) {
      float bias = gcnb[nt * 16 + m16];
#pragma unroll
      for (int r = 0; r < 4; ++r) {
        size_t grow = row0 + wv * 32 + rt * 16 + qd + r;
        Xbf[grow * DD + nt * 16 + m16] = f2bf(acc[rt][nt][r] + bias);
      }
    }
  }
}

// ---------------- K4: H1(bf16) = relu(adj_b @ X_b), BN1 stats (256 thr) ----------------
__global__ __launch_bounds__(256) void k4_adj(
    const unsigned short* __restrict__ Xbf, const float* __restrict__ adj,
    unsigned short* __restrict__ H1bf, float* __restrict__ bn1) {
  __shared__ float Xl[52 * 132];   // row 51 zeroed
  __shared__ float Al[51 * 52];
  int b = blockIdx.x, t = threadIdx.x;   // 256 threads
  int tc = t & 31, tr = t >> 5;          // tc: float4 col, tr: 0..7
  for (int idx = t; idx < 52 * 16; idx += 256) {
    int r = idx >> 4, c8 = idx & 15;
    float4 lo = make_float4(0.f, 0.f, 0.f, 0.f), hi = lo;
    if (r < CC) {
      uint4 v = ((const uint4*)(Xbf + ((size_t)b * CC + r) * DD))[c8];
      lo.x = bf2f((unsigned short)(v.x & 0xffff)); lo.y = bf2f((unsigned short)(v.x >> 16));
      lo.z = bf2f((unsigned short)(v.y & 0xffff)); lo.w = bf2f((unsigned short)(v.y >> 16));
      hi.x = bf2f((unsigned short)(v.z & 0xffff)); hi.y = bf2f((unsigned short)(v.z >> 16));
      hi.z = bf2f((unsigned short)(v.w & 0xffff)); hi.w = bf2f((unsigned short)(v.w >> 16));
    }
    ((float4*)(Xl + r * 132 + c8 * 8))[0] = lo;
    ((float4*)(Xl + r * 132 + c8 * 8))[1] = hi;
  }
  for (int idx = t; idx < 51 * 52; idx += 256) {
    int i = idx / 52, j = idx - i * 52;
    Al[idx] = (j < CC) ? adj[(size_t)b * (CC * CC) + i * CC + j] : 0.f;
  }
  __syncthreads();
  float4 acc4[7];
#pragma unroll
  for (int k = 0; k < 7; ++k) acc4[k] = make_float4(0.f, 0.f, 0.f, 0.f);
  for (int jj = 0; jj < CC; ++jj) {
    float4 xv = ((const float4*)(Xl + jj * 132))[tc];
#pragma unroll
    for (int k = 0; k < 7; ++k) {
      int i = tr + 8 * k;
      float a = (i < CC) ? Al[i * 52 + jj] : 0.f;
      acc4[k].x += a * xv.x; acc4[k].y += a * xv.y;
      acc4[k].z += a * xv.z; acc4[k].w += a * xv.w;
    }
  }
#pragma unroll
  for (int k = 0; k < 7; ++k) {
    int i = tr + 8 * k;
    if (i < CC) {
      float4 h;
      h.x = fmaxf(acc4[k].x, 0.f); h.y = fmaxf(acc4[k].y, 0.f);
      h.z = fmaxf(acc4[k].z, 0.f); h.w = fmaxf(acc4[k].w, 0.f);
      ushort4 p;
      p.x = f2bf(h.x); p.y = f2bf(h.y); p.z = f2bf(h.z); p.w = f2bf(h.w);
      ((ushort4*)(H1bf + ((size_t)b * CC + i) * DD))[tc] = p;
      float s = h.x + h.y + h.z + h.w;
      float qq = h.x * h.x + h.y * h.y + h.z * h.z + h.w * h.w;
#pragma unroll
      for (int m = 1; m < 32; m <<= 1) {
        s += __shfl_xor(s, m);
        qq += __shfl_xor(qq, m);
      }
      if (tc == 0) {
        atomicAdd(&bn1[i], s);
        atomicAdd(&bn1[64 + i], qq);
      }
    }
  }
}

// ---------------- K6: h2 = relu(adj0 @ BN1(H1)), BN2 stats ----------------
__global__ __launch_bounds__(128) void k6_row0(
    const unsigned short* __restrict__ H1bf, const float* __restrict__ adj,
    const float* __restrict__ bn1, const float* __restrict__ gamma,
    const float* __restrict__ beta, float* __restrict__ h2,
    float* __restrict__ bn2) {
  __shared__ float cj[52];
  __shared__ float td[64];
  __shared__ float reds[128], redq[128];
  int b = blockIdx.x, t = threadIdx.x;   // t == d
  const float invBD = 1.f / ((float)Bb * (float)DD);
  if (t < 64) td[t] = 0.f;
  if (t < CC) {
    float s = bn1[t], q = bn1[64 + t];
    float m = s * invBD;
    float v = fmaxf(q * invBD - m * m, 0.f);
    float inv = rsqrtf(v + 1e-5f);
    float al = gamma[t] * inv;
    float de = beta[t] - m * al;
    float a0 = adj[(size_t)b * (CC * CC) + t];
    cj[t] = a0 * al;
    td[t] = a0 * de;
  }
  __syncthreads();
  float tcst = 0.f;
  for (int j = 0; j < CC; ++j) tcst += td[j];
  float acc = tcst;
  const unsigned short* hb = H1bf + (size_t)b * CC * DD + t;
#pragma unroll 4
  for (int j = 0; j < CC; ++j) acc += cj[j] * bf2f(hb[(size_t)j * DD]);
  acc = fmaxf(acc, 0.f);
  h2[(size_t)b * DD + t] = acc;
  reds[t] = acc;
  redq[t] = acc * acc;
  __syncthreads();
  for (int s = 64; s > 0; s >>= 1) {
    if (t < s) { reds[t] += reds[t + s]; redq[t] += redq[t + s]; }
    __syncthreads();
  }
  if (t == 0) {
    atomicAdd(&bn2[0], reds[0]);
    atomicAdd(&bn2[1], redq[0]);
  }
}

// ---------------- K8: tri_em = BN2(h2) ----------------
__global__ __launch_bounds__(256) void k8_final(
    const float* __restrict__ h2, const float* __restrict__ bn2,
    const float* __restrict__ gamma, const float* __restrict__ beta,
    float* __restrict__ out) {
  int i = blockIdx.x * 256 + threadIdx.x;
  const float invBD = 1.f / ((float)Bb * (float)DD);
  float m = bn2[0] * invBD;
  float v = fmaxf(bn2[1] * invBD - m * m, 0.f);
  float inv = rsqrtf(v + 1e-5f);
  out[(size_t)3 * Bb * DD + i] = (h2[i] - m) * inv * gamma[0] + beta[0];
}

extern "C" void kernel_launch(void* const* d_in, const int* in_sizes, int n_in,
                              void* d_out, int out_size, void* d_ws, size_t ws_size,
                              hipStream_t stream) {
  (void)in_sizes; (void)n_in; (void)out_size; (void)ws_size;
  const int*   hrt   = (const int*)d_in[0];
  const int*   neb   = (const int*)d_in[1];
  const int*   nebr  = (const int*)d_in[2];
  const float* adj   = (const float*)d_in[3];
  const float* entW  = (const float*)d_in[4];
  const float* relW  = (const float*)d_in[5];
  const float* attW  = (const float*)d_in[6];
  const float* attb  = (const float*)d_in[7];
  const float* gcnW  = (const float*)d_in[8];
  const float* gcnb  = (const float*)d_in[9];
  const float* gamma = (const float*)d_in[10];
  const float* beta  = (const float*)d_in[11];
  float* out = (float*)d_out;
  char*  ws  = (char*)d_ws;

  float*          subg = (float*)(ws + OFF_SUBG);
  unsigned short* Xbf  = (unsigned short*)(ws + OFF_XBF);   // overlays subg
  unsigned short* Ybf  = (unsigned short*)(ws + OFF_Y);
  unsigned short* H1bf = (unsigned short*)(ws + OFF_H1);
  float*          bn1  = (float*)(ws + OFF_BN);
  float*          bn2  = bn1 + 128;
  float*          h2   = (float*)(ws + OFF_H2);
  float*          Mext = (float*)(ws + OFF_M);

  hipMemsetAsync((void*)bn1, 0, 1024, stream);   // zero BN accumulators

  k0_prep<<<DD, DD, 0, stream>>>(attW, attb, Mext);
  k1_gather<<<dim3(NN, Bb), 64, 0, stream>>>(neb, nebr, entW, relW, subg);
  k2_att<<<Bb, 256, 0, stream>>>(hrt, entW, relW, subg, Mext, Ybf, out);
  k3_gemm<<<(Bb * CC) / 128, 256, 0, stream>>>(Ybf, gcnW, gcnb, Xbf);
  k4_adj<<<Bb, 256, 0, stream>>>(Xbf, adj, H1bf, bn1);
  k6_row0<<<Bb, 128, 0, stream>>>(H1bf, adj, bn1, gamma, beta, h2, bn2);
  k8_final<<<(Bb * DD) / 256, 256, 0, stream>>>(h2, bn2, gamma, beta, out);
}